// Round 3
// baseline (510.633 us; speedup 1.0000x reference)
//
#include <hip/hip_runtime.h>

typedef __attribute__((ext_vector_type(8))) short short8;
typedef __attribute__((ext_vector_type(4))) float f32x4;
typedef unsigned short u16;
typedef unsigned int u32;

#define B_ 32
#define S_ 578
#define D_ 1024
#define H_ 16
#define DH_ 64
#define M_ 18496
#define MP_ 18560
#define N_ 3072
#define K_ 1024
#define BHROWS_ (B_ * H_ * S_ + 64)   /* 296000 rows: +64 pad so tail tiles can over-read */
#define SCALE2 0.18033688011112042f   /* 0.125 * log2(e) */

__device__ __forceinline__ u16 f2bf(float x) {
  u32 u = __float_as_uint(x);
  u = (u + 0x7fffu + ((u >> 16) & 1u)) >> 16;
  return (u16)u;
}

__device__ __forceinline__ void gload_lds16(const u16* g, u16* l) {
  __builtin_amdgcn_global_load_lds((const __attribute__((address_space(1))) void*)g,
                                   (__attribute__((address_space(3))) void*)l, 16, 0, 0);
}

// ---------------- prep: hidden fp32 -> bf16 ----------------
__global__ __launch_bounds__(256) void cvt_hidden(const float* __restrict__ in, u16* __restrict__ o) {
  long i = ((long)blockIdx.x * 256 + threadIdx.x) * 8;
  float4 f0 = *(const float4*)(in + i);
  float4 f1 = *(const float4*)(in + i + 4);
  short8 v;
  u16* p = (u16*)&v;
  p[0] = f2bf(f0.x); p[1] = f2bf(f0.y); p[2] = f2bf(f0.z); p[3] = f2bf(f0.w);
  p[4] = f2bf(f1.x); p[5] = f2bf(f1.y); p[6] = f2bf(f1.z); p[7] = f2bf(f1.w);
  *(short8*)(o + i) = v;
}

// ---------------- prep: W[H,D,DH] -> Wt[N,K] bf16 (B^T layout) ----------------
__global__ __launch_bounds__(256) void wt_kernel(const float* __restrict__ Wq, const float* __restrict__ Wk,
                                                 const float* __restrict__ Wv, u16* __restrict__ Wt) {
  const int d0 = blockIdx.x * 64;
  const int h = blockIdx.y;
  const int qkv = blockIdx.z;
  const float* W = (qkv == 0) ? Wq : ((qkv == 1) ? Wk : Wv);
  __shared__ float tile[64][65];
  const int t = threadIdx.x;
  {
    int e = t & 63, dr = t >> 6;
#pragma unroll
    for (int p = 0; p < 16; ++p) {
      int dd = dr + p * 4;
      tile[dd][e] = W[((long)h * D_ + d0 + dd) * DH_ + e];
    }
  }
  __syncthreads();
  {
    int dd = t & 63, er = t >> 6;
#pragma unroll
    for (int p = 0; p < 16; ++p) {
      int ee = er + p * 4;
      long n = (long)qkv * 1024 + h * 64 + ee;
      Wt[n * K_ + d0 + dd] = f2bf(tile[dd][ee]);
    }
  }
}

// ---------------- prep: pack biases into [3072] fp32 ----------------
__global__ __launch_bounds__(256) void bias_kernel(const float* __restrict__ bq, const float* __restrict__ bk,
                                                   const float* __restrict__ bv, float* __restrict__ bias) {
  int i = blockIdx.x * 256 + threadIdx.x;
  if (i < 3072) {
    const float* src = (i < 1024) ? bq : ((i < 2048) ? bk : bv);
    bias[i] = src[i & 1023];
  }
}

// ---------------- QKV GEMM: C[M,N] = A[M,K] * Wt[N,K]^T + bias ----------------
// 128x128 tile, BK=32, 16x16x32 bf16 MFMA, global_load_lds staging with
// XOR chunk swizzle (LDS slot s at row r holds global k-chunk s ^ ((r>>1)&3))
// so the ds_read_b128 fragment reads are bank-conflict-free.
__global__ __launch_bounds__(256) void qkv_gemm(const u16* __restrict__ A, const u16* __restrict__ Bt,
                                                const float* __restrict__ bias,
                                                u16* __restrict__ qb, u16* __restrict__ kb, u16* __restrict__ vb) {
  __shared__ alignas(16) u16 As[128 * 32];
  __shared__ alignas(16) u16 Bs[128 * 32];
  const int tid = threadIdx.x, wave = tid >> 6, lane = tid & 63, quad = lane >> 4, l16 = lane & 15;
  const long m0 = (long)blockIdx.x * 128, n0 = (long)blockIdx.y * 128;
  const u16* Ag = A + m0 * K_;
  const u16* Bg = Bt + n0 * K_;

  f32x4 acc[4][4];
#pragma unroll
  for (int mi = 0; mi < 4; ++mi)
#pragma unroll
    for (int ni = 0; ni < 4; ++ni) { f32x4 z = {0.f, 0.f, 0.f, 0.f}; acc[mi][ni] = z; }

  const int srow = lane >> 2;                        // staging row 0..15 within a 16-row block
  const int gchunk = (lane & 3) ^ ((lane >> 3) & 3); // swizzled global k-chunk for this lane's slot
  const int scol = gchunk * 8;
  const int r0 = 32 * wave;                          // this wave stages rows r0..r0+31 of both tiles
  const int sw = quad ^ ((l16 >> 1) & 3);            // frag-read slot swizzle (inverse of staging)
  const int rb = (wave >> 1) * 64 + l16;
  const int cb = (wave & 1) * 64 + l16;

  for (int it = 0; it < 32; ++it) {
    const int k0 = it * 32;
    gload_lds16(Ag + (long)(r0 + srow) * K_ + k0 + scol,      &As[r0 * 32 + lane * 8]);
    gload_lds16(Ag + (long)(r0 + 16 + srow) * K_ + k0 + scol, &As[(r0 + 16) * 32 + lane * 8]);
    gload_lds16(Bg + (long)(r0 + srow) * K_ + k0 + scol,      &Bs[r0 * 32 + lane * 8]);
    gload_lds16(Bg + (long)(r0 + 16 + srow) * K_ + k0 + scol, &Bs[(r0 + 16) * 32 + lane * 8]);
    __syncthreads();
    const short8* Asv = (const short8*)As;
    const short8* Bsv = (const short8*)Bs;
    short8 a[4], b2[4];
#pragma unroll
    for (int mi = 0; mi < 4; ++mi) a[mi] = Asv[(rb + mi * 16) * 4 + sw];
#pragma unroll
    for (int ni = 0; ni < 4; ++ni) b2[ni] = Bsv[(cb + ni * 16) * 4 + sw];
#pragma unroll
    for (int mi = 0; mi < 4; ++mi)
#pragma unroll
      for (int ni = 0; ni < 4; ++ni)
        acc[mi][ni] = __builtin_amdgcn_mfma_f32_16x16x32_bf16(a[mi], b2[ni], acc[mi][ni], 0, 0, 0);
    __syncthreads();
  }

  // epilogue: += bias, scatter to q/k/v [B,H,S,DH] bf16
  float bv4[4]; int hh[4], ee[4];
#pragma unroll
  for (int ni = 0; ni < 4; ++ni) {
    long n = n0 + (wave & 1) * 64 + ni * 16 + l16;
    bv4[ni] = bias[n];
    hh[ni] = (int)((n >> 6) & 15);
    ee[ni] = (int)(n & 63);
  }
  const int qkv = (int)(n0 >> 10);
  u16* dst = (qkv == 0) ? qb : ((qkv == 1) ? kb : vb);
#pragma unroll
  for (int mi = 0; mi < 4; ++mi) {
#pragma unroll
    for (int r = 0; r < 4; ++r) {
      long m = m0 + (wave >> 1) * 64 + mi * 16 + quad * 4 + r;
      if (m < M_) {
        unsigned bi = (unsigned)m / (unsigned)S_;
        unsigned si = (unsigned)m - bi * (unsigned)S_;
        long rowb = ((long)bi * H_) * S_ * DH_ + (long)si * DH_;
#pragma unroll
        for (int ni = 0; ni < 4; ++ni) {
          float v = acc[mi][ni][r] + bv4[ni];
          dst[rowb + (long)hh[ni] * (S_ * DH_) + ee[ni]] = f2bf(v);
        }
      }
    }
  }
}

// ---------------- flash attention: one block per (b, h, 64-row Q tile) ----------------
__global__ __launch_bounds__(256) void attn_kernel(const u16* __restrict__ qb, const u16* __restrict__ kb,
                                                   const u16* __restrict__ vb, float* __restrict__ out) {
  __shared__ alignas(16) u16 Ks[64 * 72];
  __shared__ alignas(16) u16 Vt[64 * 72];
  __shared__ alignas(16) u16 Ps[4 * 16 * 72];
  const int tid = threadIdx.x, wave = tid >> 6, lane = tid & 63, quad = lane >> 4, l16 = lane & 15;
  const int qt = blockIdx.x, h = blockIdx.y, b = blockIdx.z;
  const long bh = (long)b * H_ + h;
  const u16* qp = qb + bh * S_ * DH_;
  const u16* kp = kb + bh * S_ * DH_;
  const u16* vp = vb + bh * S_ * DH_;
  const int q0 = qt * 64;

  short8 qf0, qf1;
  {
    int row = q0 + wave * 16 + l16;
    const short8* qv = (const short8*)(qp + (long)row * DH_);
    qf0 = qv[quad];
    qf1 = qv[4 + quad];
  }

  f32x4 O[4];
#pragma unroll
  for (int et = 0; et < 4; ++et) { f32x4 z = {0.f, 0.f, 0.f, 0.f}; O[et] = z; }
  float l[4] = {0.f, 0.f, 0.f, 0.f};
  float mrow[4] = {-1e30f, -1e30f, -1e30f, -1e30f};

  for (int kt = 0; kt < 10; ++kt) {
    const int t0 = kt * 64;
    __syncthreads();
    // stage K as-is (rows padded to 72); V transposed with chunk swizzle:
    // Vt element (e,t) lives at e*72 + ((t>>3)^(e>>3))*8 + (t&7)
#pragma unroll
    for (int c = 0; c < 2; ++c) {
      int idx = tid + 256 * c;
      int row = idx >> 3, col8 = (idx & 7) * 8;
      const short8 kv = *(const short8*)(kp + (long)(t0 + row) * DH_ + col8);
      *(short8*)(&Ks[row * 72 + col8]) = kv;
      const short8 vv = *(const short8*)(vp + (long)(t0 + row) * DH_ + col8);
      const u16* ve = (const u16*)&vv;
      int slot = (((row >> 3) ^ (idx & 7)) * 8) + (row & 7);
#pragma unroll
      for (int j = 0; j < 8; ++j) Vt[(col8 + j) * 72 + slot] = ve[j];
    }
    __syncthreads();

    // QK^T -> scores in exp2 domain
    float p[4][4];
    const short8* Kv8 = (const short8*)Ks;
#pragma unroll
    for (int jt = 0; jt < 4; ++jt) {
      f32x4 sacc = {0.f, 0.f, 0.f, 0.f};
      short8 kf0 = Kv8[(16 * jt + l16) * 9 + quad];
      short8 kf1 = Kv8[(16 * jt + l16) * 9 + 4 + quad];
      sacc = __builtin_amdgcn_mfma_f32_16x16x32_bf16(qf0, kf0, sacc, 0, 0, 0);
      sacc = __builtin_amdgcn_mfma_f32_16x16x32_bf16(qf1, kf1, sacc, 0, 0, 0);
      int col = t0 + 16 * jt + l16;
      bool valid = (col < S_);
#pragma unroll
      for (int r = 0; r < 4; ++r) p[jt][r] = valid ? sacc[r] * SCALE2 : -1e30f;
    }

    // online softmax (this wave owns q-rows quad*4+r; 16 lanes of a quad = 16 cols)
#pragma unroll
    for (int r = 0; r < 4; ++r) {
      float mx = fmaxf(fmaxf(p[0][r], p[1][r]), fmaxf(p[2][r], p[3][r]));
      mx = fmaxf(mx, __shfl_xor(mx, 1));
      mx = fmaxf(mx, __shfl_xor(mx, 2));
      mx = fmaxf(mx, __shfl_xor(mx, 4));
      mx = fmaxf(mx, __shfl_xor(mx, 8));
      float mnew = fmaxf(mrow[r], mx);
      float alpha = exp2f(mrow[r] - mnew);
      mrow[r] = mnew;
      float rs = 0.f;
#pragma unroll
      for (int jt = 0; jt < 4; ++jt) { p[jt][r] = exp2f(p[jt][r] - mnew); rs += p[jt][r]; }
      rs += __shfl_xor(rs, 1);
      rs += __shfl_xor(rs, 2);
      rs += __shfl_xor(rs, 4);
      rs += __shfl_xor(rs, 8);
      l[r] = l[r] * alpha + rs;
      // rescale ONLY component r of each O vector: O[et][r] is query-row r's
      // accumulator (C-layout: row = quad*4 + reg). Scaling the whole f32x4
      // here was the R2 bug (every row got prod of all four alphas).
#pragma unroll
      for (int et = 0; et < 4; ++et) O[et][r] *= alpha;
    }

    // P (C-layout) -> LDS -> A-layout frags; wave-private region, no barrier needed
    u16* Pw = Ps + wave * 16 * 72;
#pragma unroll
    for (int jt = 0; jt < 4; ++jt)
#pragma unroll
      for (int r = 0; r < 4; ++r)
        Pw[(quad * 4 + r) * 72 + 16 * jt + l16] = f2bf(p[jt][r]);

    const short8* Pv8 = (const short8*)(Ps + wave * 16 * 72);
    const short8* Vv8 = (const short8*)Vt;
#pragma unroll
    for (int ks = 0; ks < 2; ++ks) {
      short8 pa = Pv8[l16 * 9 + ks * 4 + quad];
#pragma unroll
      for (int et = 0; et < 4; ++et) {
        short8 vf = Vv8[(16 * et + l16) * 9 + ((ks * 4 + quad) ^ (2 * et + (l16 >> 3)))];
        O[et] = __builtin_amdgcn_mfma_f32_16x16x32_bf16(pa, vf, O[et], 0, 0, 0);
      }
    }
  }

  // epilogue: normalize and store fp32 [B,S,H*DH]
  float inv[4];
#pragma unroll
  for (int r = 0; r < 4; ++r) inv[r] = 1.0f / l[r];
#pragma unroll
  for (int et = 0; et < 4; ++et)
#pragma unroll
    for (int r = 0; r < 4; ++r) {
      int s = q0 + wave * 16 + quad * 4 + r;
      if (s < S_) out[((long)b * S_ + s) * (H_ * DH_) + (long)h * DH_ + et * 16 + l16] = O[et][r] * inv[r];
    }
}

extern "C" void kernel_launch(void* const* d_in, const int* in_sizes, int n_in,
                              void* d_out, int out_size, void* d_ws, size_t ws_size,
                              hipStream_t stream) {
  const float* hs = (const float*)d_in[0];
  const float* Wq = (const float*)d_in[1];
  const float* bq = (const float*)d_in[2];
  const float* Wk = (const float*)d_in[3];
  const float* bk = (const float*)d_in[4];
  const float* Wv = (const float*)d_in[5];
  const float* bv = (const float*)d_in[6];
  float* out = (float*)d_out;

  u16* Abf = (u16*)d_ws;                                   // [MP_, K_] bf16
  u16* Wt = Abf + (size_t)MP_ * K_;                        // [N_, K_] bf16
  float* bias = (float*)(Wt + (size_t)N_ * K_);            // [N_] fp32
  u16* qb = (u16*)(bias + N_);                             // [BHROWS_, DH_] bf16
  u16* kb = qb + (size_t)BHROWS_ * DH_;
  u16* vb = kb + (size_t)BHROWS_ * DH_;

  cvt_hidden<<<dim3(9248), dim3(256), 0, stream>>>(hs, Abf);
  wt_kernel<<<dim3(16, 16, 3), dim3(256), 0, stream>>>(Wq, Wk, Wv, Wt);
  bias_kernel<<<dim3(12), dim3(256), 0, stream>>>(bq, bk, bv, bias);
  qkv_gemm<<<dim3(145, 24), dim3(256), 0, stream>>>(Abf, Wt, bias, qb, kb, vb);
  attn_kernel<<<dim3(10, 16, 32), dim3(256), 0, stream>>>(qb, kb, vb, out);
}

// Round 4
// 478.806 us; speedup vs baseline: 1.0665x; 1.0665x over previous
//
#include <hip/hip_runtime.h>

typedef __attribute__((ext_vector_type(8))) short short8;
typedef __attribute__((ext_vector_type(4))) float f32x4;
typedef unsigned short u16;
typedef unsigned int u32;

#define B_ 32
#define S_ 578
#define D_ 1024
#define H_ 16
#define DH_ 64
#define M_ 18496
#define MP_ 18560
#define N_ 3072
#define K_ 1024
#define ST_ 640                        /* padded seq len for e-major V rows */
#define BHROWS_ (B_ * H_ * S_ + 64)    /* 296000 rows: +64 pad for tail-tile over-read */
#define SCALE2 0.18033688011112042f    /* 0.125 * log2(e) */
#define CMAX 16.0f                     /* fixed softmax offset (exp2 domain); |scores*SCALE2| << 16 */

__device__ __forceinline__ u16 f2bf(float x) {
  u32 u = __float_as_uint(x);
  u = (u + 0x7fffu + ((u >> 16) & 1u)) >> 16;
  return (u16)u;
}

__device__ __forceinline__ void gload_lds16(const u16* g, u16* l) {
  __builtin_amdgcn_global_load_lds((const __attribute__((address_space(1))) void*)g,
                                   (__attribute__((address_space(3))) void*)l, 16, 0, 0);
}

// ---------------- prep: hidden fp32 -> bf16 ----------------
__global__ __launch_bounds__(256) void cvt_hidden(const float* __restrict__ in, u16* __restrict__ o) {
  long i = ((long)blockIdx.x * 256 + threadIdx.x) * 8;
  float4 f0 = *(const float4*)(in + i);
  float4 f1 = *(const float4*)(in + i + 4);
  short8 v;
  u16* p = (u16*)&v;
  p[0] = f2bf(f0.x); p[1] = f2bf(f0.y); p[2] = f2bf(f0.z); p[3] = f2bf(f0.w);
  p[4] = f2bf(f1.x); p[5] = f2bf(f1.y); p[6] = f2bf(f1.z); p[7] = f2bf(f1.w);
  *(short8*)(o + i) = v;
}

// ---------------- prep: W[H,D,DH] -> Wt[N,K] bf16 (B^T layout) ----------------
__global__ __launch_bounds__(256) void wt_kernel(const float* __restrict__ Wq, const float* __restrict__ Wk,
                                                 const float* __restrict__ Wv, u16* __restrict__ Wt) {
  const int d0 = blockIdx.x * 64;
  const int h = blockIdx.y;
  const int qkv = blockIdx.z;
  const float* W = (qkv == 0) ? Wq : ((qkv == 1) ? Wk : Wv);
  __shared__ float tile[64][65];
  const int t = threadIdx.x;
  {
    int e = t & 63, dr = t >> 6;
#pragma unroll
    for (int p = 0; p < 16; ++p) {
      int dd = dr + p * 4;
      tile[dd][e] = W[((long)h * D_ + d0 + dd) * DH_ + e];
    }
  }
  __syncthreads();
  {
    int dd = t & 63, er = t >> 6;
#pragma unroll
    for (int p = 0; p < 16; ++p) {
      int ee = er + p * 4;
      long n = (long)qkv * 1024 + h * 64 + ee;
      Wt[n * K_ + d0 + dd] = f2bf(tile[dd][ee]);
    }
  }
}

// ---------------- prep: pack biases into [3072] fp32 ----------------
__global__ __launch_bounds__(256) void bias_kernel(const float* __restrict__ bq, const float* __restrict__ bk,
                                                   const float* __restrict__ bv, float* __restrict__ bias) {
  int i = blockIdx.x * 256 + threadIdx.x;
  if (i < 3072) {
    const float* src = (i < 1024) ? bq : ((i < 2048) ? bk : bv);
    bias[i] = src[i & 1023];
  }
}

// ---------------- QKV GEMM: C[M,N] = A[M,K] * Wt[N,K]^T + bias ----------------
// 128x128 tile, BK=32, 16x16x32 bf16 MFMA, global_load_lds staging, XOR chunk swizzle.
// Q,K stored [bh][s][e]; V stored e-major [bh][e][s] (ST_=640 row) so attention
// can stage Vt with global_load_lds instead of an in-kernel scalar transpose.
__global__ __launch_bounds__(256) void qkv_gemm(const u16* __restrict__ A, const u16* __restrict__ Bt,
                                                const float* __restrict__ bias,
                                                u16* __restrict__ qb, u16* __restrict__ kb, u16* __restrict__ vbt) {
  __shared__ alignas(16) u16 As[128 * 32];
  __shared__ alignas(16) u16 Bs[128 * 32];
  const int tid = threadIdx.x, wave = tid >> 6, lane = tid & 63, quad = lane >> 4, l16 = lane & 15;
  const long m0 = (long)blockIdx.x * 128, n0 = (long)blockIdx.y * 128;
  const u16* Ag = A + m0 * K_;
  const u16* Bg = Bt + n0 * K_;

  f32x4 acc[4][4];
#pragma unroll
  for (int mi = 0; mi < 4; ++mi)
#pragma unroll
    for (int ni = 0; ni < 4; ++ni) { f32x4 z = {0.f, 0.f, 0.f, 0.f}; acc[mi][ni] = z; }

  const int srow = lane >> 2;                        // staging row 0..15 within a 16-row block
  const int gchunk = (lane & 3) ^ ((lane >> 3) & 3); // swizzled global k-chunk for this lane's slot
  const int scol = gchunk * 8;
  const int r0 = 32 * wave;
  const int sw = quad ^ ((l16 >> 1) & 3);            // frag-read slot swizzle (inverse of staging)
  const int rb = (wave >> 1) * 64 + l16;
  const int cb = (wave & 1) * 64 + l16;

  for (int it = 0; it < 32; ++it) {
    const int k0 = it * 32;
    gload_lds16(Ag + (long)(r0 + srow) * K_ + k0 + scol,      &As[r0 * 32 + lane * 8]);
    gload_lds16(Ag + (long)(r0 + 16 + srow) * K_ + k0 + scol, &As[(r0 + 16) * 32 + lane * 8]);
    gload_lds16(Bg + (long)(r0 + srow) * K_ + k0 + scol,      &Bs[r0 * 32 + lane * 8]);
    gload_lds16(Bg + (long)(r0 + 16 + srow) * K_ + k0 + scol, &Bs[(r0 + 16) * 32 + lane * 8]);
    __syncthreads();
    const short8* Asv = (const short8*)As;
    const short8* Bsv = (const short8*)Bs;
    short8 a[4], b2[4];
#pragma unroll
    for (int mi = 0; mi < 4; ++mi) a[mi] = Asv[(rb + mi * 16) * 4 + sw];
#pragma unroll
    for (int ni = 0; ni < 4; ++ni) b2[ni] = Bsv[(cb + ni * 16) * 4 + sw];
#pragma unroll
    for (int mi = 0; mi < 4; ++mi)
#pragma unroll
      for (int ni = 0; ni < 4; ++ni)
        acc[mi][ni] = __builtin_amdgcn_mfma_f32_16x16x32_bf16(a[mi], b2[ni], acc[mi][ni], 0, 0, 0);
    __syncthreads();
  }

  // epilogue: += bias; scatter q/k to [B,H,S,DH], v to e-major [B,H,DH,ST_]
  float bv4[4]; int hh[4], ee[4];
#pragma unroll
  for (int ni = 0; ni < 4; ++ni) {
    long n = n0 + (wave & 1) * 64 + ni * 16 + l16;
    bv4[ni] = bias[n];
    hh[ni] = (int)((n >> 6) & 15);
    ee[ni] = (int)(n & 63);
  }
  const int qkv = (int)(n0 >> 10);
  if (qkv == 2) {
#pragma unroll
    for (int mi = 0; mi < 4; ++mi) {
#pragma unroll
      for (int r = 0; r < 4; ++r) {
        long m = m0 + (wave >> 1) * 64 + mi * 16 + quad * 4 + r;
        if (m < M_) {
          unsigned bi = (unsigned)m / (unsigned)S_;
          unsigned si = (unsigned)m - bi * (unsigned)S_;
#pragma unroll
          for (int ni = 0; ni < 4; ++ni) {
            float v = acc[mi][ni][r] + bv4[ni];
            vbt[((long)(bi * H_ + hh[ni]) * DH_ + ee[ni]) * ST_ + si] = f2bf(v);
          }
        }
      }
    }
  } else {
    u16* dst = (qkv == 0) ? qb : kb;
#pragma unroll
    for (int mi = 0; mi < 4; ++mi) {
#pragma unroll
      for (int r = 0; r < 4; ++r) {
        long m = m0 + (wave >> 1) * 64 + mi * 16 + quad * 4 + r;
        if (m < M_) {
          unsigned bi = (unsigned)m / (unsigned)S_;
          unsigned si = (unsigned)m - bi * (unsigned)S_;
          long rowb = ((long)bi * H_) * S_ * DH_ + (long)si * DH_;
#pragma unroll
          for (int ni = 0; ni < 4; ++ni) {
            float v = acc[mi][ni][r] + bv4[ni];
            dst[rowb + (long)hh[ni] * (S_ * DH_) + ee[ni]] = f2bf(v);
          }
        }
      }
    }
  }
}

// ---------------- flash attention, fixed-max softmax, full gload_lds staging ----------------
// One block per (b, h, 64-row Q tile). K tile [t][e] and Vt tile [e][t] both 64x64,
// packed rows of 8 16B chunks; global-side XOR swizzle (lane fetches chunk (l&7)^(row&7))
// makes the packed LDS layout conflict-free for b128 frag reads.
__global__ __launch_bounds__(256) void attn_kernel(const u16* __restrict__ qb, const u16* __restrict__ kb,
                                                   const u16* __restrict__ vbt, float* __restrict__ out) {
  __shared__ alignas(16) u16 Ks[64 * 64];
  __shared__ alignas(16) u16 Vs[64 * 64];
  __shared__ alignas(16) u16 Ps[4 * 16 * 72];
  const int tid = threadIdx.x, wave = tid >> 6, lane = tid & 63, quad = lane >> 4, l16 = lane & 15;
  const int qt = blockIdx.x, h = blockIdx.y, b = blockIdx.z;
  const long bh = (long)b * H_ + h;
  const u16* qp = qb + bh * S_ * DH_;
  const u16* kp = kb + bh * S_ * DH_;
  const u16* vtp = vbt + bh * DH_ * ST_;
  const int q0 = qt * 64;

  short8 qf0, qf1;
  {
    int row = q0 + wave * 16 + l16;
    const short8* qv = (const short8*)(qp + (long)row * DH_);
    qf0 = qv[quad];
    qf1 = qv[4 + quad];
  }

  f32x4 O[4];
#pragma unroll
  for (int et = 0; et < 4; ++et) { f32x4 z = {0.f, 0.f, 0.f, 0.f}; O[et] = z; }
  float lp[4] = {0.f, 0.f, 0.f, 0.f};

  // staging geometry: pass p covers rows 32p..32p+31; lane handles row (tid>>3)+32p,
  // fetching global chunk (tid&7)^(row&7) into LDS linear slot tid&7 (dst = base + lane*16).
  const int srow0 = tid >> 3;
  const int slot = tid & 7;
  const int s0 = quad ^ (l16 & 7);  // frag-read slot for chunk `quad` at row with (row&7)==(l16&7)

  for (int kt = 0; kt < 10; ++kt) {
    const int t0 = kt * 64;
    __syncthreads();
#pragma unroll
    for (int p = 0; p < 2; ++p) {
      int row = srow0 + 32 * p;
      int gch = slot ^ (row & 7);
      gload_lds16(kp + (long)(t0 + row) * DH_ + gch * 8, &Ks[(tid + 256 * p) * 8]);
      gload_lds16(vtp + (long)row * ST_ + t0 + gch * 8, &Vs[(tid + 256 * p) * 8]);
    }
    __syncthreads();

    // QK^T -> p = exp2(score*SCALE2 - CMAX), masked
    float p[4][4];
    const short8* Kv8 = (const short8*)Ks;
#pragma unroll
    for (int jt = 0; jt < 4; ++jt) {
      f32x4 sacc = {0.f, 0.f, 0.f, 0.f};
      short8 kf0 = Kv8[(16 * jt + l16) * 8 + s0];
      short8 kf1 = Kv8[(16 * jt + l16) * 8 + ((quad + 4) ^ (l16 & 7))];
      sacc = __builtin_amdgcn_mfma_f32_16x16x32_bf16(qf0, kf0, sacc, 0, 0, 0);
      sacc = __builtin_amdgcn_mfma_f32_16x16x32_bf16(qf1, kf1, sacc, 0, 0, 0);
      bool valid = (t0 + 16 * jt + l16) < S_;
#pragma unroll
      for (int r = 0; r < 4; ++r) {
        float e = valid ? exp2f(sacc[r] * SCALE2 - CMAX) : 0.f;
        p[jt][r] = e;
        lp[r] += e;
      }
    }

    // P (C-layout) -> LDS -> A-layout frags; wave-private region, no barrier needed
    u16* Pw = Ps + wave * 16 * 72;
#pragma unroll
    for (int jt = 0; jt < 4; ++jt)
#pragma unroll
      for (int r = 0; r < 4; ++r)
        Pw[(quad * 4 + r) * 72 + 16 * jt + l16] = f2bf(p[jt][r]);

    const short8* Pv8 = (const short8*)(Ps + wave * 16 * 72);
    const short8* Vv8 = (const short8*)Vs;
#pragma unroll
    for (int ks = 0; ks < 2; ++ks) {
      short8 pa = Pv8[l16 * 9 + ks * 4 + quad];
#pragma unroll
      for (int et = 0; et < 4; ++et) {
        short8 vf = Vv8[(16 * et + l16) * 8 + ((ks * 4 + quad) ^ (l16 & 7))];
        O[et] = __builtin_amdgcn_mfma_f32_16x16x32_bf16(pa, vf, O[et], 0, 0, 0);
      }
    }
  }

  // reduce row sums across the quad's 16 lanes, normalize, store fp32 [B,S,H*DH]
  float inv[4];
#pragma unroll
  for (int r = 0; r < 4; ++r) {
    float s = lp[r];
    s += __shfl_xor(s, 1);
    s += __shfl_xor(s, 2);
    s += __shfl_xor(s, 4);
    s += __shfl_xor(s, 8);
    inv[r] = 1.0f / s;
  }
#pragma unroll
  for (int et = 0; et < 4; ++et)
#pragma unroll
    for (int r = 0; r < 4; ++r) {
      int s = q0 + wave * 16 + quad * 4 + r;
      if (s < S_) out[((long)b * S_ + s) * (H_ * DH_) + (long)h * DH_ + et * 16 + l16] = O[et][r] * inv[r];
    }
}

extern "C" void kernel_launch(void* const* d_in, const int* in_sizes, int n_in,
                              void* d_out, int out_size, void* d_ws, size_t ws_size,
                              hipStream_t stream) {
  const float* hs = (const float*)d_in[0];
  const float* Wq = (const float*)d_in[1];
  const float* bq = (const float*)d_in[2];
  const float* Wk = (const float*)d_in[3];
  const float* bk = (const float*)d_in[4];
  const float* Wv = (const float*)d_in[5];
  const float* bv = (const float*)d_in[6];
  float* out = (float*)d_out;

  u16* Abf = (u16*)d_ws;                                   // [MP_, K_] bf16
  u16* Wt = Abf + (size_t)MP_ * K_;                        // [N_, K_] bf16
  float* bias = (float*)(Wt + (size_t)N_ * K_);            // [N_] fp32
  u16* qb = (u16*)(bias + N_);                             // [BHROWS_, DH_] bf16
  u16* kb = qb + (size_t)BHROWS_ * DH_;                    // [BHROWS_, DH_] bf16
  u16* vbt = kb + (size_t)BHROWS_ * DH_;                   // [B*H, DH_, ST_] bf16 (e-major)

  cvt_hidden<<<dim3(9248), dim3(256), 0, stream>>>(hs, Abf);
  wt_kernel<<<dim3(16, 16, 3), dim3(256), 0, stream>>>(Wq, Wk, Wv, Wt);
  bias_kernel<<<dim3(12), dim3(256), 0, stream>>>(bq, bk, bv, bias);
  qkv_gemm<<<dim3(145, 24), dim3(256), 0, stream>>>(Abf, Wt, bias, qb, kb, vbt);
  attn_kernel<<<dim3(10, 16, 32), dim3(256), 0, stream>>>(qb, kb, vbt, out);
}